// Round 9
// baseline (96.087 us; speedup 1.0000x reference)
//
#include <hip/hip_runtime.h>
#include <stdint.h>

#define S_INV (1.0f / 7.0f)
#define COORD_W 5.0f
#define NOOBJ_W 0.5f

// Round-9: clean waves/CU A/B vs round-4. 2-wave blocks (128 thr) share a
// double-buffered 128-cell chunk. Combined buffer 30720 B = 30 x 1024:
// wave 0 stages the 'out' half (15 x width-16 gll), wave 1 the 'tgt' half
// (15 x width-16) -- identical load shape to round 4. Counted vmcnt(15)
// steady state; raw s_barrier (NOT __syncthreads -- that drains vmcnt(0)).
// LDS/block = 61440 B -> 2 blocks/CU = 8 waves/CU = 2 waves/SIMD (2x R4),
// full-lane compute (cell == tid).
// Buffer layout (floats): [0,3840) = 128 'out' cells, [3840,7680) = 'tgt'.
#define CHUNK_CELLS 128
#define BUF_FLOATS 7680                     // 30720 B per buffer
#define ARR_BYTES  15360                    // per-array bytes per chunk

typedef const __attribute__((address_space(1))) void* gp1_t;
typedef __attribute__((address_space(3))) void* lp3_t;

__device__ __forceinline__ void stage_half(const float* __restrict__ arr,
                                           size_t cb, float* buf,
                                           int wave, int lane)
{
    // wave 0: 'out' -> buf[0,15360) ; wave 1: 'tgt' -> buf[15360,30720)
    char* dst = (char*)buf + wave * ARR_BYTES;
#pragma unroll
    for (int j = 0; j < 15; ++j) {
        const char* src = (const char*)arr + cb + j * 1024 + lane * 16;
        // LDS dest = wave-uniform base; HW adds lane*16.
        __builtin_amdgcn_global_load_lds((gp1_t)src, (lp3_t)(dst + j * 1024),
                                         16, 0, 0);
    }
}

__global__ __launch_bounds__(128) void yolo_loss_kernel(
    const float* __restrict__ outp, const float* __restrict__ tgtp,
    float* __restrict__ ws, int nchunks, int nblocks)
{
    __shared__ float lds[2 * BUF_FLOATS];   // 61440 B

    const int tid  = threadIdx.x;           // 0..127 == cell within chunk
    const int wave = tid >> 6;
    const int lane = tid & 63;

    float* bufA = lds;
    float* bufB = lds + BUF_FLOATS;
    const float* myarr = wave ? tgtp : outp;

    float acc_total = 0.f, acc_iou = 0.f, acc_acc = 0.f;

    stage_half(myarr, (size_t)blockIdx.x * ARR_BYTES, bufA, wave, lane);
    int cur = 0;

    for (int m = blockIdx.x; m < nchunks; m += nblocks) {
        const bool has_next = (m + nblocks) < nchunks;   // block-uniform
        float* bnext = cur ? bufA : bufB;
        float* bcur  = cur ? bufB : bufA;

        if (has_next) {
            stage_half(myarr, (size_t)(m + nblocks) * ARR_BYTES, bnext, wave, lane);
            // outstanding = 30 (15 cur + 15 next); wait to 15 -> cur complete,
            // next buffer's 15 loads stay in flight across compute.
            asm volatile("s_waitcnt vmcnt(15)" ::: "memory");
        } else {
            asm volatile("s_waitcnt vmcnt(0)" ::: "memory");
        }
        __builtin_amdgcn_sched_barrier(0);
        __builtin_amdgcn_s_barrier();        // partner's cur loads also done
        __builtin_amdgcn_sched_barrier(0);   // rule #18: no reads hoisted above

        // ---- read own cell (stride 120 B: 4-way bank alias, acceptable) ----
        const float* oc = bcur + tid * 30;
        const float* tc = bcur + 3840 + tid * 30;
        float ov[30], tv[30];
#pragma unroll
        for (int i = 0; i < 15; ++i) {
            float2 a = *reinterpret_cast<const float2*>(oc + 2 * i);
            float2 b = *reinterpret_cast<const float2*>(tc + 2 * i);
            ov[2 * i] = a.x; ov[2 * i + 1] = a.y;
            tv[2 * i] = b.x; tv[2 * i + 1] = b.y;
        }

        float w_obj = (tv[4] > 0.f) ? 1.f : 0.f;
        float w_no = 1.f - w_obj;

        // class loss + argmax accuracy (first-max tie-break)
        float cls = 0.f;
        float omax = ov[10]; int oarg = 0;
        float tmax = tv[10]; int targ = 0;
#pragma unroll
        for (int c = 0; c < 20; ++c) {
            float d = ov[10 + c] - tv[10 + c];
            cls += d * d;
            if (ov[10 + c] > omax) { omax = ov[10 + c]; oarg = c; }
            if (tv[10 + c] > tmax) { tmax = tv[10 + c]; targ = c; }
        }

        // IOU of both predicted boxes vs target box 0
        float t_x = tv[0] * S_INV, t_y = tv[1] * S_INV;
        float t_w = tv[2], t_h = tv[3];
        float t_l = t_x - 0.5f * t_w, t_r = t_x + 0.5f * t_w;
        float t_t = t_y - 0.5f * t_h, t_b = t_y + 0.5f * t_h;
        float area_t = t_w * t_h;

        float iou0, iou1;
        {
            float x = ov[0] * S_INV, y = ov[1] * S_INV;
            float w = ov[2], h = ov[3];
            float l = x - 0.5f * w, r = x + 0.5f * w;
            float tt = y - 0.5f * h, bb = y + 0.5f * h;
            float iw = fmaxf(fminf(r, t_r) - fmaxf(l, t_l), 0.f);
            float ih = fmaxf(fminf(bb, t_b) - fmaxf(tt, t_t), 0.f);
            float inter = iw * ih;
            iou0 = inter / (w * h + area_t - inter);
        }
        {
            float x = ov[5] * S_INV, y = ov[6] * S_INV;
            float w = ov[7], h = ov[8];
            float l = x - 0.5f * w, r = x + 0.5f * w;
            float tt = y - 0.5f * h, bb = y + 0.5f * h;
            float iw = fmaxf(fminf(r, t_r) - fmaxf(l, t_l), 0.f);
            float ih = fmaxf(fminf(bb, t_b) - fmaxf(tt, t_t), 0.f);
            float inter = iw * ih;
            iou1 = inter / (w * h + area_t - inter);
        }

        bool r1 = (iou1 > iou0);
        float max_iou = r1 ? iou1 : iou0;

        float os0 = r1 ? ov[5] : ov[0];
        float os1 = r1 ? ov[6] : ov[1];
        float os2 = r1 ? ov[7] : ov[2];
        float os3 = r1 ? ov[8] : ov[3];
        float os4 = r1 ? ov[9] : ov[4];
        float ts0 = r1 ? tv[5] : tv[0];
        float ts1 = r1 ? tv[6] : tv[1];
        float ts2 = r1 ? tv[7] : tv[2];
        float ts3 = r1 ? tv[8] : tv[3];
        float oa4 = r1 ? ov[4] : ov[9];

        float d0 = os0 - ts0, d1 = os1 - ts1;
        float d2 = sqrtf(os2) - sqrtf(ts2);
        float d3 = sqrtf(os3) - sqrtf(ts3);
        float coord = d0 * d0 + d1 * d1 + d2 * d2 + d3 * d3;

        float dc = os4 - max_iou;
        float conf = dc * dc;
        float aband = oa4 * oa4;
        float n0 = ov[4] - tv[4], n1 = ov[9] - tv[9];
        float noobj = n0 * n0 + n1 * n1;

        acc_total += w_obj * (COORD_W * coord + conf + NOOBJ_W * aband + cls)
                   + NOOBJ_W * w_no * noobj;
        acc_iou   += w_obj * max_iou;
        acc_acc   += w_obj * ((oarg == targ) ? 1.f : 0.f);

        __builtin_amdgcn_sched_barrier(0);
        __builtin_amdgcn_s_barrier();        // both waves done reading bcur (WAR)
        __builtin_amdgcn_sched_barrier(0);
        cur ^= 1;
    }

    // ---- wave-local reduction; lane 0 writes SoA partials ----
#pragma unroll
    for (int off = 32; off > 0; off >>= 1) {
        acc_total += __shfl_down(acc_total, off);
        acc_iou   += __shfl_down(acc_iou, off);
        acc_acc   += __shfl_down(acc_acc, off);
    }
    const int gwid = blockIdx.x * 2 + wave;
    const int nwaves = nblocks * 2;
    if (lane == 0) {
        ws[gwid]              = acc_total;
        ws[nwaves + gwid]     = acc_iou;
        ws[2 * nwaves + gwid] = acc_acc;
    }
}

__global__ __launch_bounds__(256) void yolo_reduce_kernel(
    const float* __restrict__ ws, float* __restrict__ out, int nwaves)
{
    float t0 = 0.f, t1 = 0.f, t2 = 0.f;
    for (int i = threadIdx.x; i < nwaves; i += blockDim.x) {
        t0 += ws[i];
        t1 += ws[nwaves + i];
        t2 += ws[2 * nwaves + i];
    }
#pragma unroll
    for (int off = 32; off > 0; off >>= 1) {
        t0 += __shfl_down(t0, off);
        t1 += __shfl_down(t1, off);
        t2 += __shfl_down(t2, off);
    }
    __shared__ float s[3][4];
    int wave = threadIdx.x >> 6;
    int lane = threadIdx.x & 63;
    if (lane == 0) { s[0][wave] = t0; s[1][wave] = t1; s[2][wave] = t2; }
    __syncthreads();
    if (threadIdx.x == 0) {
        float a0 = 0.f, a1 = 0.f, a2 = 0.f;
#pragma unroll
        for (int w = 0; w < 4; ++w) { a0 += s[0][w]; a1 += s[1][w]; a2 += s[2][w]; }
        out[0] = a0;   // total
        out[1] = a1;   // sum_iou
        out[2] = a2;   // accurate_num
    }
}

extern "C" void kernel_launch(void* const* d_in, const int* in_sizes, int n_in,
                              void* d_out, int out_size, void* d_ws, size_t ws_size,
                              hipStream_t stream) {
    const float* outp = (const float*)d_in[0];
    const float* tgtp = (const float*)d_in[1];
    float* ws = (float*)d_ws;
    float* o = (float*)d_out;

    const int ncells  = in_sizes[0] / 30;        // 32768*7*7 = 1,605,632
    const int nchunks = ncells / CHUNK_CELLS;    // 12,544 (exact)
    const int blocks  = 640;                     // 2 blocks/CU (LDS-resident)
    const int nwaves  = blocks * 2;              // 1280

    yolo_loss_kernel<<<blocks, 128, 0, stream>>>(outp, tgtp, ws, nchunks, blocks);
    yolo_reduce_kernel<<<1, 256, 0, stream>>>(ws, o, nwaves);
}